// Round 9
// baseline (216.072 us; speedup 1.0000x reference)
//
#include <hip/hip_runtime.h>
#include <stdint.h>

#pragma clang fp contract(off)

typedef unsigned long long ull;

#define HIGHT 0.7f
#define LOWT  0.3f
#define KSEL  128
#define CAP   2048         // candidate buffer per mode
#define MAXGT 512
#define TPB   256
#define CHUNK 64           // proposals per fused_iou block
#define TJ    128          // j-tile for the shared IoU matrix
#define SMP   132          // smat pitch: bank (4p+j)%32 -> worst 2-way (free)
#define NLAD  7

// counter layout (int cnts[32]):
// [0] posMask  [1] negMask(normal)  [2] notPos
// [3..9] pos ladder  [10..16] neg-normal ladder  [17..23] neg-fallback ladder
// [24] collect cnt pos  [25] collect cnt neg
__device__ __constant__ float LADV[NLAD] = {0.998f, 0.99f, 0.95f, 0.8f, 0.5f, 0.25f, 0.0625f};

// ---- bit-exact IoU (numpy fp32 op-for-op; no contraction; IEEE div) ----
__device__ __forceinline__ float iou_pair(float ax0, float ay0, float ax1, float ay1, float aarea,
                                          float bx0, float by0, float bx1, float by1, float barea){
#pragma clang fp contract(off)
  float x0 = fmaxf(ax0, bx0);
  float y0 = fmaxf(ay0, by0);
  float x1 = fminf(ax1, bx1);
  float y1 = fminf(ay1, by1);
  float dx = fmaxf(x1 - x0, 0.0f);
  float dy = fmaxf(y1 - y0, 0.0f);
  float inter = dx * dy;
  float uni = (aarea + barea) - inter;
  return inter / uni;
}

// signed-compare CAS max: ws poison (0xAA.. = negative) loses to any real key (>=0)
__device__ __forceinline__ void atomic_smax(ull* addr, ull key){
  long long cur = (long long)*addr;
  while ((long long)key > cur){
    long long prev = (long long)atomicCAS(addr, (ull)cur, key);
    if (prev == cur) break;
    cur = prev;
  }
}

// ---- K1: zero forced + row max/argmax + shared-IoU col reduce + provisional counts ----
__global__ __launch_bounds__(TPB)
void fused_iou(const float4* __restrict__ boxes, const float4* __restrict__ gts,
               int n1, int n2, int nblk,
               float* __restrict__ max_iou, int* __restrict__ input_idx,
               ull* __restrict__ colbest, int* __restrict__ forced,
               int* __restrict__ cnts_part,
               const float* __restrict__ pn, const float* __restrict__ nn)
{
#pragma clang fp contract(off)
  const int b = blockIdx.x, t = threadIdx.x;

  // distributed zeroing of forced flags (written by fixup, read by collect)
  for (int x = b * TPB + t; x < n1; x += nblk * TPB) forced[x] = 0;

  __shared__ float4 gc[MAXGT];
  __shared__ float  ga[MAXGT];
  __shared__ float  smat[CHUNK * SMP];   // 64 x 132 fp32 = 33.8 KB
  __shared__ float  sm[CHUNK];

  for (int j = t; j < n2; j += TPB){
    float4 g = gts[j];
    float hw = g.z * 0.5f, hh = g.w * 0.5f;
    gc[j] = make_float4(g.x - hw, g.y - hh, g.x + hw, g.y + hh);
    ga[j] = g.z * g.w;
  }
  __syncthreads();

  const int lo = b * CHUNK;
  int cr = n1 - lo; if (cr > CHUNK) cr = CHUNK; if (cr < 0) cr = 0;

  const int pi = t >> 2, q = t & 3;
  const bool valid = (pi < cr);
  float px0 = 0, py0 = 0, px1 = 0, py1 = 0, pa = 0;
  if (valid){
    float4 pb = boxes[lo + pi];
    float hw = pb.z * 0.5f, hh = pb.w * 0.5f;
    px0 = pb.x - hw; py0 = pb.y - hh; px1 = pb.x + hw; py1 = pb.y + hh;
    pa = pb.z * pb.w;
  }
  float vA = -1.0f, vB = -1.0f; int jA = 0, jB = 0;   // row argmax chains

  for (int tb = 0; tb < n2; tb += TJ){
    const int tn = min(TJ, n2 - tb);
    // row compute: quarter q covers j = tb+q+4s; each IoU stored once in smat.
    // Two independent chains (j0, j0+4) overlap the fp32-div latency.
    if (valid){
      const int jlim = tb + tn;
      int s = 0;
      for (;; s += 2){
        int j0 = tb + q + 4 * s;
        int j1 = j0 + 4;
        if (j1 < jlim){
          float4 g0 = gc[j0]; float a0 = ga[j0];
          float4 g1 = gc[j1]; float a1 = ga[j1];
          float u = iou_pair(px0, py0, px1, py1, pa, g0.x, g0.y, g0.z, g0.w, a0);
          float w = iou_pair(px0, py0, px1, py1, pa, g1.x, g1.y, g1.z, g1.w, a1);
          smat[pi * SMP + (j0 - tb)] = u;
          smat[pi * SMP + (j1 - tb)] = w;
          if (u > vA){ vA = u; jA = j0; }
          if (w > vB){ vB = w; jB = j1; }
        } else {
          if (j0 < jlim){
            float4 g0 = gc[j0]; float a0 = ga[j0];
            float u = iou_pair(px0, py0, px1, py1, pa, g0.x, g0.y, g0.z, g0.w, a0);
            smat[pi * SMP + (j0 - tb)] = u;
            if (u > vA){ vA = u; jA = j0; }
          }
          break;
        }
      }
    }
    __syncthreads();
    // col reduce of the tile from LDS: 2 threads per j (p-halves of 32)
    {
      const int jloc = t >> 1, half = t & 1;
      if (jloc < tn){
        float cv = -1.0f; int cp = 0;
        const int p0 = half * 32;
        const int p1 = min(p0 + 32, cr);
        for (int p = p0; p < p1; ++p){
          float v = smat[p * SMP + jloc];           // strict > asc p = first max
          if (v > cv){ cv = v; cp = p; }
        }
        float ov = __shfl_xor(cv, 1, 64);
        int   op = __shfl_xor(cp, 1, 64);
        if (ov > cv || (ov == cv && op < cp)){ cv = ov; cp = op; }
        if (half == 0 && cv >= 0.0f){
          ull key = ((ull)__float_as_uint(cv) << 32) | (ull)(unsigned)~(unsigned)(lo + cp);
          atomic_smax(&colbest[tb + jloc], key);
        }
      }
    }
    __syncthreads();
  }

  // merge the 4 quarters of the row argmax (tie -> lower j)
  if (vB > vA || (vB == vA && jB < jA)){ vA = vB; jA = jB; }
  #pragma unroll
  for (int m = 1; m <= 2; m <<= 1){
    float ov = __shfl_xor(vA, m, 64);
    int   oj = __shfl_xor(jA, m, 64);
    if (ov > vA || (ov == vA && oj < jA)){ vA = ov; jA = oj; }
  }
  if (valid && q == 0){
    max_iou[lo + pi] = vA;
    input_idx[lo + pi] = jA;
    sm[pi] = vA;
  }
  __syncthreads();

  // provisional counts (ignore forced; fixup corrects): wave 0, 1 proposal/lane
  if (t < 64){
    const bool vld = (t < cr);
    float m = vld ? sm[t] : -1.0f;
    bool pos = vld && (m > HIGHT);
    bool nm  = vld && (m < LOWT);
    bool np  = vld && !(m > HIGHT);
    float sp = pos ? pn[lo + t] : -1.0f;
    float sn = (nm || np) ? nn[lo + t] : -1.0f;
    int c[24];
    c[0] = __popcll(__ballot(pos));
    c[1] = __popcll(__ballot(nm));
    c[2] = __popcll(__ballot(np));
    #pragma unroll
    for (int k = 0; k < NLAD; ++k){
      float L = LADV[k];
      c[3 + k]  = __popcll(__ballot(pos && sp > L));
      c[10 + k] = __popcll(__ballot(nm  && sn > L));
      c[17 + k] = __popcll(__ballot(np  && sn > L));
    }
    if (t == 0){
      #pragma unroll
      for (int k = 0; k < 24; ++k) cnts_part[b * 24 + k] = c[k];
    }
  }
}

// ---- K2 (1 block): reduce cnts_part + forced scatter + exact count corrections ----
__global__ __launch_bounds__(512)
void fixup_kernel(const ull* __restrict__ colbest, int n1, int n2, int nblk,
                  const float* __restrict__ max_iou,
                  const float* __restrict__ pn, const float* __restrict__ nn,
                  int* __restrict__ forced, const int* __restrict__ cnts_part,
                  int* __restrict__ cnts)
{
  __shared__ int lc[26];
  const int t = threadIdx.x;
  if (t < 26) lc[t] = 0;
  __syncthreads();
  const int tot = nblk * 24;
  for (int x = t; x < tot; x += 512){
    int v = cnts_part[x];
    if (v) atomicAdd(&lc[x % 24], v);
  }
  if (t < n2){
    unsigned idx = ~(unsigned)(colbest[t] & 0xFFFFFFFFull);
    if (idx < (unsigned)n1){
      int old = atomicExch(&forced[idx], 1);      // dedupe: first writer corrects
      if (old == 0){
        float m = max_iou[idx];
        if (!(m > HIGHT)){                        // forcing flips this row to pos
          float sp = pn[idx];
          float sn = nn[idx];
          atomicAdd(&lc[0], 1);
          atomicAdd(&lc[2], -1);
          #pragma unroll
          for (int k = 0; k < NLAD; ++k){
            float L = LADV[k];
            if (sp > L) atomicAdd(&lc[3 + k], 1);
            if (sn > L) atomicAdd(&lc[17 + k], -1);
          }
          if (m < LOWT){
            atomicAdd(&lc[1], -1);
            #pragma unroll
            for (int k = 0; k < NLAD; ++k)
              if (sn > LADV[k]) atomicAdd(&lc[10 + k], -1);
          }
        }
      }
    }
  }
  __syncthreads();
  if (t < 26) cnts[t] = lc[t];                    // [24],[25] = 0: collect counters
}

// ---- tau: largest ladder level with >= KSEL survivors (exact superset) ----
__device__ __forceinline__ float pick_tau(const int* lad, int tot){
  if (tot <= CAP) return -1.0f;       // collect all masked (exact, covers fill)
  for (int k = 0; k < NLAD; ++k)
    if (lad[k] >= KSEL) return LADV[k];
  return -1.0f;
}

// ---- K3: grid-wide collect into global cand buffers ----
__global__ __launch_bounds__(TPB)
void collect_kernel(const float* __restrict__ max_iou, const int* __restrict__ forced,
                    const float* __restrict__ pn, const float* __restrict__ nn,
                    int n1, int* __restrict__ cnts, ull* __restrict__ cand)
{
  __shared__ int s_c[24];
  const int t = threadIdx.x;
  if (t < 24) s_c[t] = cnts[t];
  __syncthreads();
  const bool fb = (s_c[1] == 0);                 // no negatives -> complement of pos
  const int totP = s_c[0];
  const int totN = fb ? s_c[2] : s_c[1];
  const float tauP = pick_tau(&s_c[3], totP);
  const float tauN = pick_tau(fb ? &s_c[17] : &s_c[10], totN);

  const int i = blockIdx.x * TPB + t;
  if (i >= n1) return;
  float m = max_iou[i];
  bool f = forced[i] != 0;
  bool pos = (m > HIGHT) || f;
  // Key: (bits(score)+1)<<32 | ~i (score in [0,1) -> bits monotone; +1 so the
  // fill key (k32=0) loses to a real 0.0 score).
  if (pos){
    float sc = pn[i];
    if (sc > tauP){
      int p = atomicAdd(&cnts[24], 1);
      if (p < CAP) cand[p] = ((ull)(__float_as_uint(sc) + 1u) << 32) | (ull)(unsigned)~(unsigned)i;
    }
  } else if (totP < KSEL && i < 2 * KSEL){
    // ref top_k fills with -1-scored entries in ascending index; all needed
    // fills have index < 2*KSEL
    int p = atomicAdd(&cnts[24], 1);
    if (p < CAP) cand[p] = (ull)(unsigned)~(unsigned)i;
  }
  bool seln = fb ? (!pos) : ((m < LOWT) && !f);
  if (seln){
    float sc = nn[i];
    if (sc > tauN){
      int p = atomicAdd(&cnts[25], 1);
      if (p < CAP) cand[CAP + p] = ((ull)(__float_as_uint(sc) + 1u) << 32) | (ull)(unsigned)~(unsigned)i;
    }
  } else if (totN < KSEL && i < 2 * KSEL){
    int p = atomicAdd(&cnts[25], 1);
    if (p < CAP) cand[CAP + p] = (ull)(unsigned)~(unsigned)i;
  }
}

// ---- K4: exact rank-select of top-128 per mode (keys totally ordered, unique) ----
__global__ __launch_bounds__(1024)
void select_kernel(const ull* __restrict__ cand, const int* __restrict__ cnts,
                   const int* __restrict__ input_idx, int* __restrict__ out)
{
  const int t = threadIdx.x;
  const bool isPos = (blockIdx.x == 0);
  __shared__ ull keys[CAP];
  int n = cnts[isPos ? 24 : 25]; if (n > CAP) n = CAP;
  for (int x = t; x < n; x += 1024)
    keys[x] = cand[(isPos ? 0 : CAP) + x];
  __syncthreads();
  ull mk[2]; int mr[2]; int ne = 0;
  for (int x = t; x < n; x += 1024){ mk[ne] = keys[x]; mr[ne] = 0; ++ne; }
  for (int o = 0; o < n; ++o){
    ull ko = keys[o];                             // uniform addr -> LDS broadcast
    if (ne > 0) mr[0] += (ko > mk[0]);
    if (ne > 1) mr[1] += (ko > mk[1]);
  }
  for (int e = 0; e < ne; ++e){
    int r = mr[e];
    if (r < KSEL){
      unsigned idx = ~(unsigned)(mk[e] & 0xFFFFFFFFull);
      if (isPos){ out[r] = (int)idx; out[KSEL + r] = input_idx[idx]; }
      else        out[2 * KSEL + r] = (int)idx;
    }
  }
}

extern "C" void kernel_launch(void* const* d_in, const int* in_sizes, int n_in,
                              void* d_out, int out_size, void* d_ws, size_t ws_size,
                              hipStream_t stream){
  const float4* boxes = (const float4*)d_in[0];
  const float4* gts   = (const float4*)d_in[1];
  const float* pos_noise = (const float*)d_in[2];
  const float* neg_noise = (const float*)d_in[3];
  const int n1 = in_sizes[0] / 4;
  const int n2 = in_sizes[1] / 4;
  int* out = (int*)d_out;

  char* ws = (char*)d_ws;
  size_t off = 0;
  auto carve = [&](size_t bytes) -> char* {
    char* p = ws + off;
    off = (off + bytes + 255) & ~(size_t)255;
    return p;
  };
  const int nblk = (n1 + CHUNK - 1) / CHUNK;       // 782
  float* max_iou   = (float*)carve((size_t)n1 * 4);
  int*   input_idx = (int*)  carve((size_t)n1 * 4);
  ull*   colbest   = (ull*)  carve((size_t)n2 * 8);   // no init: CAS-max is signed,
                                                      // 0xAA.. poison always loses
  int*   forced    = (int*)  carve((size_t)n1 * 4);
  int*   cnts_part = (int*)  carve((size_t)nblk * 24 * 4);
  int*   cnts      = (int*)  carve(32 * 4);
  ull*   cand      = (ull*)  carve((size_t)2 * CAP * 8);

  const int gb = (n1 + TPB - 1) / TPB;             // 196
  fused_iou<<<nblk, TPB, 0, stream>>>(boxes, gts, n1, n2, nblk,
                                      max_iou, input_idx, colbest, forced,
                                      cnts_part, pos_noise, neg_noise);
  fixup_kernel<<<1, 512, 0, stream>>>(colbest, n1, n2, nblk, max_iou,
                                      pos_noise, neg_noise, forced, cnts_part, cnts);
  collect_kernel<<<gb, TPB, 0, stream>>>(max_iou, forced, pos_noise, neg_noise,
                                         n1, cnts, cand);
  select_kernel<<<2, 1024, 0, stream>>>(cand, cnts, input_idx, out);
}

// Round 10
// 151.020 us; speedup vs baseline: 1.4308x; 1.4308x over previous
//
#include <hip/hip_runtime.h>
#include <stdint.h>

#pragma clang fp contract(off)

typedef unsigned long long ull;

#define HIGHT 0.7f
#define LOWT  0.3f
#define KSEL  128
#define CAP   2048         // candidate buffer per mode
#define MAXGT 512
#define TPB   256
#define CHUNK 64           // proposals per fused_iou block
#define TJ    64           // j-tile for the shared IoU matrix
#define SMP   66           // smat pitch: write bank (2*pi+q)%32 -> 2-way (free)
#define NLAD  7

// counter layout (int cnts[32]):
// [0] posMask  [1] negMask(normal)  [2] notPos
// [3..9] pos ladder  [10..16] neg-normal ladder  [17..23] neg-fallback ladder
// [24] collect cnt pos  [25] collect cnt neg
__device__ __constant__ float LADV[NLAD] = {0.998f, 0.99f, 0.95f, 0.8f, 0.5f, 0.25f, 0.0625f};

// ---- bit-exact IoU (numpy fp32 op-for-op; no contraction; IEEE div) ----
__device__ __forceinline__ float iou_pair(float ax0, float ay0, float ax1, float ay1, float aarea,
                                          float bx0, float by0, float bx1, float by1, float barea){
#pragma clang fp contract(off)
  float x0 = fmaxf(ax0, bx0);
  float y0 = fmaxf(ay0, by0);
  float x1 = fminf(ax1, bx1);
  float y1 = fminf(ay1, by1);
  float dx = fmaxf(x1 - x0, 0.0f);
  float dy = fmaxf(y1 - y0, 0.0f);
  float inter = dx * dy;
  float uni = (aarea + barea) - inter;
  return inter / uni;
}

// ---- K1: zero forced + row max/argmax + LDS-tile col partials + provisional counts ----
__global__ __launch_bounds__(TPB)
void fused_iou(const float4* __restrict__ boxes, const float4* __restrict__ gts,
               int n1, int n2, int nblk,
               float* __restrict__ max_iou, int* __restrict__ input_idx,
               ull* __restrict__ colpart, int* __restrict__ forced,
               int* __restrict__ cnts_part,
               const float* __restrict__ pn, const float* __restrict__ nn)
{
#pragma clang fp contract(off)
  const int b = blockIdx.x, t = threadIdx.x;

  // distributed zeroing of forced flags (written by fixup, read by collect)
  for (int x = b * TPB + t; x < n1; x += nblk * TPB) forced[x] = 0;

  __shared__ float4 gc[MAXGT];
  __shared__ float  ga[MAXGT];
  __shared__ float  smat[CHUNK * SMP];   // 64 x 66 fp32 = 16.9 KB
  __shared__ float  sm[CHUNK];

  for (int j = t; j < n2; j += TPB){
    float4 g = gts[j];
    float hw = g.z * 0.5f, hh = g.w * 0.5f;
    gc[j] = make_float4(g.x - hw, g.y - hh, g.x + hw, g.y + hh);
    ga[j] = g.z * g.w;
  }
  __syncthreads();

  const int lo = b * CHUNK;
  int cr = n1 - lo; if (cr > CHUNK) cr = CHUNK; if (cr < 0) cr = 0;

  const int pi = t >> 2, q = t & 3;
  const bool valid = (pi < cr);
  float px0 = 0, py0 = 0, px1 = 0, py1 = 0, pa = 0;
  if (valid){
    float4 pb = boxes[lo + pi];
    float hw = pb.z * 0.5f, hh = pb.w * 0.5f;
    px0 = pb.x - hw; py0 = pb.y - hh; px1 = pb.x + hw; py1 = pb.y + hh;
    pa = pb.z * pb.w;
  }
  float vA = -1.0f, vB = -1.0f; int jA = 0, jB = 0;   // row argmax chains

  for (int tb = 0; tb < n2; tb += TJ){
    const int tn = min(TJ, n2 - tb);
    // row compute: quarter q covers j = tb+q+4s; each IoU stored once in smat.
    // Two independent chains (j0, j0+4) overlap the fp32-div latency.
    if (valid){
      const int jlim = tb + tn;
      int s = 0;
      for (;; s += 2){
        int j0 = tb + q + 4 * s;
        int j1 = j0 + 4;
        if (j1 < jlim){
          float4 g0 = gc[j0]; float a0 = ga[j0];
          float4 g1 = gc[j1]; float a1 = ga[j1];
          float u = iou_pair(px0, py0, px1, py1, pa, g0.x, g0.y, g0.z, g0.w, a0);
          float w = iou_pair(px0, py0, px1, py1, pa, g1.x, g1.y, g1.z, g1.w, a1);
          smat[pi * SMP + (j0 - tb)] = u;
          smat[pi * SMP + (j1 - tb)] = w;
          if (u > vA){ vA = u; jA = j0; }
          if (w > vB){ vB = w; jB = j1; }
        } else {
          if (j0 < jlim){
            float4 g0 = gc[j0]; float a0 = ga[j0];
            float u = iou_pair(px0, py0, px1, py1, pa, g0.x, g0.y, g0.z, g0.w, a0);
            smat[pi * SMP + (j0 - tb)] = u;
            if (u > vA){ vA = u; jA = j0; }
          }
          break;
        }
      }
    }
    __syncthreads();
    // col reduce of the tile from LDS: 4 threads/j, blocked p-chains of 16.
    // Chain qp covers p in [16qp, 16qp+16): disjoint ascending ranges, so the
    // quad merge's "lower cp on tie" = global first-occurrence argmax.
    {
      const int jloc = t >> 2, qp = t & 3;
      if (jloc < tn){
        float cv = -1.0f; int cp = 0;
        const int p0 = qp * 16;
        const int p1 = min(p0 + 16, cr);
        for (int p = p0; p < p1; ++p){
          float v = smat[p * SMP + jloc];
          if (v > cv){ cv = v; cp = p; }
        }
        #pragma unroll
        for (int m = 1; m <= 2; m <<= 1){
          float ov = __shfl_xor(cv, m, 64);
          int   op = __shfl_xor(cp, m, 64);
          if (ov > cv || (ov == cv && op < cp)){ cv = ov; cp = op; }
        }
        if (qp == 0){
          // key: bits(nonneg IoU)<<32 | ~globalIdx -> max = best val, tie lowest idx
          colpart[(size_t)b * n2 + (tb + jloc)] =
            ((ull)__float_as_uint(cv) << 32) | (ull)(unsigned)~(unsigned)(lo + cp);
        }
      }
    }
    __syncthreads();
  }

  // merge the 4 quarters of the row argmax (tie -> lower j)
  if (vB > vA || (vB == vA && jB < jA)){ vA = vB; jA = jB; }
  #pragma unroll
  for (int m = 1; m <= 2; m <<= 1){
    float ov = __shfl_xor(vA, m, 64);
    int   oj = __shfl_xor(jA, m, 64);
    if (ov > vA || (ov == vA && oj < jA)){ vA = ov; jA = oj; }
  }
  if (valid && q == 0){
    max_iou[lo + pi] = vA;
    input_idx[lo + pi] = jA;
    sm[pi] = vA;
  }
  __syncthreads();

  // provisional counts (ignore forced; fixup corrects): wave 0, 1 proposal/lane
  if (t < 64){
    const bool vld = (t < cr);
    float m = vld ? sm[t] : -1.0f;
    bool pos = vld && (m > HIGHT);
    bool nm  = vld && (m < LOWT);
    bool np  = vld && !(m > HIGHT);
    float sp = pos ? pn[lo + t] : -1.0f;
    float sn = (nm || np) ? nn[lo + t] : -1.0f;
    int c[24];
    c[0] = __popcll(__ballot(pos));
    c[1] = __popcll(__ballot(nm));
    c[2] = __popcll(__ballot(np));
    #pragma unroll
    for (int k = 0; k < NLAD; ++k){
      float L = LADV[k];
      c[3 + k]  = __popcll(__ballot(pos && sp > L));
      c[10 + k] = __popcll(__ballot(nm  && sn > L));
      c[17 + k] = __popcll(__ballot(np  && sn > L));
    }
    if (t == 0){
      #pragma unroll
      for (int k = 0; k < 24; ++k) cnts_part[b * 24 + k] = c[k];
    }
  }
}

// ---- K2: per-GT max over block partials -> colbest (plain reduce, no atomics) ----
__global__ __launch_bounds__(TPB)
void colreduce(const ull* __restrict__ colpart, int n2, int nblk,
               ull* __restrict__ colbest)
{
  const int jj = blockIdx.x, t = threadIdx.x;
  ull m = 0;
  for (int x = t; x < nblk; x += TPB){
    ull v = colpart[(size_t)x * n2 + jj];
    if (v > m) m = v;
  }
  __shared__ ull red[TPB];
  red[t] = m;
  __syncthreads();
  for (int s = TPB >> 1; s > 0; s >>= 1){
    if (t < s && red[t + s] > red[t]) red[t] = red[t + s];
    __syncthreads();
  }
  if (t == 0) colbest[jj] = red[0];
}

// ---- K3 (1 block): reduce cnts_part + forced scatter + exact count corrections ----
__global__ __launch_bounds__(512)
void fixup_kernel(const ull* __restrict__ colbest, int n1, int n2, int nblk,
                  const float* __restrict__ max_iou,
                  const float* __restrict__ pn, const float* __restrict__ nn,
                  int* __restrict__ forced, const int* __restrict__ cnts_part,
                  int* __restrict__ cnts)
{
  __shared__ int lc[26];
  const int t = threadIdx.x;
  if (t < 26) lc[t] = 0;
  __syncthreads();
  const int tot = nblk * 24;
  for (int x = t; x < tot; x += 512){
    int v = cnts_part[x];
    if (v) atomicAdd(&lc[x % 24], v);
  }
  if (t < n2){
    unsigned idx = ~(unsigned)(colbest[t] & 0xFFFFFFFFull);
    if (idx < (unsigned)n1){
      int old = atomicExch(&forced[idx], 1);      // dedupe: first writer corrects
      if (old == 0){
        float m = max_iou[idx];
        if (!(m > HIGHT)){                        // forcing flips this row to pos
          float sp = pn[idx];
          float sn = nn[idx];
          atomicAdd(&lc[0], 1);
          atomicAdd(&lc[2], -1);
          #pragma unroll
          for (int k = 0; k < NLAD; ++k){
            float L = LADV[k];
            if (sp > L) atomicAdd(&lc[3 + k], 1);
            if (sn > L) atomicAdd(&lc[17 + k], -1);
          }
          if (m < LOWT){
            atomicAdd(&lc[1], -1);
            #pragma unroll
            for (int k = 0; k < NLAD; ++k)
              if (sn > LADV[k]) atomicAdd(&lc[10 + k], -1);
          }
        }
      }
    }
  }
  __syncthreads();
  if (t < 26) cnts[t] = lc[t];                    // [24],[25] = 0: collect counters
}

// ---- tau: largest ladder level with >= KSEL survivors (exact superset) ----
__device__ __forceinline__ float pick_tau(const int* lad, int tot){
  if (tot <= CAP) return -1.0f;       // collect all masked (exact, covers fill)
  for (int k = 0; k < NLAD; ++k)
    if (lad[k] >= KSEL) return LADV[k];
  return -1.0f;
}

// ---- K4: grid-wide collect into global cand buffers ----
__global__ __launch_bounds__(TPB)
void collect_kernel(const float* __restrict__ max_iou, const int* __restrict__ forced,
                    const float* __restrict__ pn, const float* __restrict__ nn,
                    int n1, int* __restrict__ cnts, ull* __restrict__ cand)
{
  __shared__ int s_c[24];
  const int t = threadIdx.x;
  if (t < 24) s_c[t] = cnts[t];
  __syncthreads();
  const bool fb = (s_c[1] == 0);                 // no negatives -> complement of pos
  const int totP = s_c[0];
  const int totN = fb ? s_c[2] : s_c[1];
  const float tauP = pick_tau(&s_c[3], totP);
  const float tauN = pick_tau(fb ? &s_c[17] : &s_c[10], totN);

  const int i = blockIdx.x * TPB + t;
  if (i >= n1) return;
  float m = max_iou[i];
  bool f = forced[i] != 0;
  bool pos = (m > HIGHT) || f;
  // Key: (bits(score)+1)<<32 | ~i (score in [0,1) -> bits monotone; +1 so the
  // fill key (k32=0) loses to a real 0.0 score).
  if (pos){
    float sc = pn[i];
    if (sc > tauP){
      int p = atomicAdd(&cnts[24], 1);
      if (p < CAP) cand[p] = ((ull)(__float_as_uint(sc) + 1u) << 32) | (ull)(unsigned)~(unsigned)i;
    }
  } else if (totP < KSEL && i < 2 * KSEL){
    // ref top_k fills with -1-scored entries in ascending index; all needed
    // fills have index < 2*KSEL
    int p = atomicAdd(&cnts[24], 1);
    if (p < CAP) cand[p] = (ull)(unsigned)~(unsigned)i;
  }
  bool seln = fb ? (!pos) : ((m < LOWT) && !f);
  if (seln){
    float sc = nn[i];
    if (sc > tauN){
      int p = atomicAdd(&cnts[25], 1);
      if (p < CAP) cand[CAP + p] = ((ull)(__float_as_uint(sc) + 1u) << 32) | (ull)(unsigned)~(unsigned)i;
    }
  } else if (totN < KSEL && i < 2 * KSEL){
    int p = atomicAdd(&cnts[25], 1);
    if (p < CAP) cand[CAP + p] = (ull)(unsigned)~(unsigned)i;
  }
}

// ---- K5: exact rank-select of top-128 per mode (keys totally ordered, unique) ----
__global__ __launch_bounds__(1024)
void select_kernel(const ull* __restrict__ cand, const int* __restrict__ cnts,
                   const int* __restrict__ input_idx, int* __restrict__ out)
{
  const int t = threadIdx.x;
  const bool isPos = (blockIdx.x == 0);
  __shared__ ull keys[CAP];
  int n = cnts[isPos ? 24 : 25]; if (n > CAP) n = CAP;
  for (int x = t; x < n; x += 1024)
    keys[x] = cand[(isPos ? 0 : CAP) + x];
  __syncthreads();
  ull mk[2]; int mr[2]; int ne = 0;
  for (int x = t; x < n; x += 1024){ mk[ne] = keys[x]; mr[ne] = 0; ++ne; }
  for (int o = 0; o < n; ++o){
    ull ko = keys[o];                             // uniform addr -> LDS broadcast
    if (ne > 0) mr[0] += (ko > mk[0]);
    if (ne > 1) mr[1] += (ko > mk[1]);
  }
  for (int e = 0; e < ne; ++e){
    int r = mr[e];
    if (r < KSEL){
      unsigned idx = ~(unsigned)(mk[e] & 0xFFFFFFFFull);
      if (isPos){ out[r] = (int)idx; out[KSEL + r] = input_idx[idx]; }
      else        out[2 * KSEL + r] = (int)idx;
    }
  }
}

extern "C" void kernel_launch(void* const* d_in, const int* in_sizes, int n_in,
                              void* d_out, int out_size, void* d_ws, size_t ws_size,
                              hipStream_t stream){
  const float4* boxes = (const float4*)d_in[0];
  const float4* gts   = (const float4*)d_in[1];
  const float* pos_noise = (const float*)d_in[2];
  const float* neg_noise = (const float*)d_in[3];
  const int n1 = in_sizes[0] / 4;
  const int n2 = in_sizes[1] / 4;
  int* out = (int*)d_out;

  char* ws = (char*)d_ws;
  size_t off = 0;
  auto carve = [&](size_t bytes) -> char* {
    char* p = ws + off;
    off = (off + bytes + 255) & ~(size_t)255;
    return p;
  };
  const int nblk = (n1 + CHUNK - 1) / CHUNK;       // 782
  float* max_iou   = (float*)carve((size_t)n1 * 4);
  int*   input_idx = (int*)  carve((size_t)n1 * 4);
  ull*   colpart   = (ull*)  carve((size_t)nblk * n2 * 8);
  ull*   colbest   = (ull*)  carve((size_t)n2 * 8);
  int*   forced    = (int*)  carve((size_t)n1 * 4);
  int*   cnts_part = (int*)  carve((size_t)nblk * 24 * 4);
  int*   cnts      = (int*)  carve(32 * 4);
  ull*   cand      = (ull*)  carve((size_t)2 * CAP * 8);

  const int gb = (n1 + TPB - 1) / TPB;             // 196
  fused_iou<<<nblk, TPB, 0, stream>>>(boxes, gts, n1, n2, nblk,
                                      max_iou, input_idx, colpart, forced,
                                      cnts_part, pos_noise, neg_noise);
  colreduce<<<n2, TPB, 0, stream>>>(colpart, n2, nblk, colbest);
  fixup_kernel<<<1, 512, 0, stream>>>(colbest, n1, n2, nblk, max_iou,
                                      pos_noise, neg_noise, forced, cnts_part, cnts);
  collect_kernel<<<gb, TPB, 0, stream>>>(max_iou, forced, pos_noise, neg_noise,
                                         n1, cnts, cand);
  select_kernel<<<2, 1024, 0, stream>>>(cand, cnts, input_idx, out);
}

// Round 11
// 136.043 us; speedup vs baseline: 1.5883x; 1.1101x over previous
//
#include <hip/hip_runtime.h>
#include <stdint.h>

#pragma clang fp contract(off)

typedef unsigned long long ull;

#define HIGHT 0.7f
#define LOWT  0.3f
#define KSEL  128
#define CAP   2048         // candidate buffer per mode
#define MAXGT 512
#define TPB   256
#define CHUNK 32           // proposals per fused_iou block (8 threads/proposal)
#define TJ    128          // j-tile for the shared IoU matrix
#define SMP   132          // pitch%32==4: write bank 4pi+q+8s (2-way), read bank 4s+jloc (free)
#define NLAD  7

// counter layout (int cnts[32]):
// [0] posMask  [1] negMask(normal)  [2] notPos
// [3..9] pos ladder  [10..16] neg-normal ladder  [17..23] neg-fallback ladder
// [24] collect cnt pos  [25] collect cnt neg
__device__ __constant__ float LADV[NLAD] = {0.998f, 0.99f, 0.95f, 0.8f, 0.5f, 0.25f, 0.0625f};

// ---- bit-exact IoU (numpy fp32 op-for-op; no contraction; IEEE div) ----
__device__ __forceinline__ float iou_pair(float ax0, float ay0, float ax1, float ay1, float aarea,
                                          float bx0, float by0, float bx1, float by1, float barea){
#pragma clang fp contract(off)
  float x0 = fmaxf(ax0, bx0);
  float y0 = fmaxf(ay0, by0);
  float x1 = fminf(ax1, bx1);
  float y1 = fminf(ay1, by1);
  float dx = fmaxf(x1 - x0, 0.0f);
  float dy = fmaxf(y1 - y0, 0.0f);
  float inter = dx * dy;
  float uni = (aarea + barea) - inter;
  return inter / uni;
}

// ---- K1: zero forced/cnts + row max/argmax + LDS-tile col partials + provisional counts ----
__global__ __launch_bounds__(TPB)
void fused_iou(const float4* __restrict__ boxes, const float4* __restrict__ gts,
               int n1, int n2, int nblk,
               float* __restrict__ max_iou, int* __restrict__ input_idx,
               ull* __restrict__ colpart, int* __restrict__ forced,
               int* __restrict__ cnts_part, int* __restrict__ cnts,
               const float* __restrict__ pn, const float* __restrict__ nn)
{
#pragma clang fp contract(off)
  const int b = blockIdx.x, t = threadIdx.x;

  // distributed zeroing (consumed by later kernels; stream order suffices)
  for (int x = b * TPB + t; x < n1; x += nblk * TPB) forced[x] = 0;
  if (b == 0 && t < 32) cnts[t] = 0;

  __shared__ float4 gc[MAXGT];
  __shared__ float  ga[MAXGT];
  __shared__ float  smat[CHUNK * SMP];   // 32 x 132 fp32 = 16.9 KB
  __shared__ float  sm[CHUNK];

  for (int j = t; j < n2; j += TPB){
    float4 g = gts[j];
    float hw = g.z * 0.5f, hh = g.w * 0.5f;
    gc[j] = make_float4(g.x - hw, g.y - hh, g.x + hw, g.y + hh);
    ga[j] = g.z * g.w;
  }
  __syncthreads();

  const int lo = b * CHUNK;
  int cr = n1 - lo; if (cr > CHUNK) cr = CHUNK; if (cr < 0) cr = 0;

  const int pi = t >> 3, q = t & 7;      // 8 threads per proposal
  const bool valid = (pi < cr);
  float px0 = 0, py0 = 0, px1 = 0, py1 = 0, pa = 0;
  if (valid){
    float4 pb = boxes[lo + pi];
    float hw = pb.z * 0.5f, hh = pb.w * 0.5f;
    px0 = pb.x - hw; py0 = pb.y - hh; px1 = pb.x + hw; py1 = pb.y + hh;
    pa = pb.z * pb.w;
  }
  float vA = -1.0f, vB = -1.0f; int jA = 0, jB = 0;   // row argmax chains

  for (int tb = 0; tb < n2; tb += TJ){
    const int tn = min(TJ, n2 - tb);
    // row compute: octant q covers j = tb+q+8s; each IoU stored once in smat.
    // Two independent chains (j0, j0+8) overlap the fp32-div latency.
    // smat write bank: (4pi + q + 8s)%32 -> worst 2-way (free).
    if (valid){
      const int jlim = tb + tn;
      int s = 0;
      for (;; s += 2){
        int j0 = tb + q + 8 * s;
        int j1 = j0 + 8;
        if (j1 < jlim){
          float4 g0 = gc[j0]; float a0 = ga[j0];
          float4 g1 = gc[j1]; float a1 = ga[j1];
          float u = iou_pair(px0, py0, px1, py1, pa, g0.x, g0.y, g0.z, g0.w, a0);
          float w = iou_pair(px0, py0, px1, py1, pa, g1.x, g1.y, g1.z, g1.w, a1);
          smat[pi * SMP + (j0 - tb)] = u;
          smat[pi * SMP + (j1 - tb)] = w;
          if (u > vA){ vA = u; jA = j0; }
          if (w > vB){ vB = w; jB = j1; }
        } else {
          if (j0 < jlim){
            float4 g0 = gc[j0]; float a0 = ga[j0];
            float u = iou_pair(px0, py0, px1, py1, pa, g0.x, g0.y, g0.z, g0.w, a0);
            smat[pi * SMP + (j0 - tb)] = u;
            if (u > vA){ vA = u; jA = j0; }
          }
          break;
        }
      }
    }
    __syncthreads();
    // col reduce: 2 threads/j, blocked p-chains of 16 (disjoint ascending ->
    // merge lower-p on tie = global first occurrence). Read bank:
    // (4s + jloc)%32 across a wave -> conflict-free.
    {
      const int jloc = t >> 1, half = t & 1;
      if (jloc < tn){
        float cv = -1.0f; int cp = 0;
        const int p0 = half * 16;
        const int p1 = min(p0 + 16, cr);
        for (int p = p0; p < p1; ++p){
          float v = smat[p * SMP + jloc];
          if (v > cv){ cv = v; cp = p; }
        }
        float ov = __shfl_xor(cv, 1, 64);
        int   op = __shfl_xor(cp, 1, 64);
        if (ov > cv || (ov == cv && op < cp)){ cv = ov; cp = op; }
        if (half == 0){
          // key: bits(nonneg IoU)<<32 | ~globalIdx -> max = best val, tie lowest idx
          colpart[(size_t)b * n2 + (tb + jloc)] =
            ((ull)__float_as_uint(cv) << 32) | (ull)(unsigned)~(unsigned)(lo + cp);
        }
      }
    }
    __syncthreads();
  }

  // merge the 8 octants of the row argmax (tie -> lower j)
  if (vB > vA || (vB == vA && jB < jA)){ vA = vB; jA = jB; }
  #pragma unroll
  for (int m = 1; m <= 4; m <<= 1){
    float ov = __shfl_xor(vA, m, 64);
    int   oj = __shfl_xor(jA, m, 64);
    if (ov > vA || (ov == vA && oj < jA)){ vA = ov; jA = oj; }
  }
  if (valid && q == 0){
    max_iou[lo + pi] = vA;
    input_idx[lo + pi] = jA;
    sm[pi] = vA;
  }
  __syncthreads();

  // provisional counts (ignore forced; colfix corrects): wave 0, lane t = proposal
  if (t < 64){
    const bool vld = (t < cr);
    float m = vld ? sm[t] : -1.0f;
    bool pos = vld && (m > HIGHT);
    bool nm  = vld && (m < LOWT);
    bool np  = vld && !(m > HIGHT);
    float sp = pos ? pn[lo + t] : -1.0f;
    float sn = (nm || np) ? nn[lo + t] : -1.0f;
    int c[24];
    c[0] = __popcll(__ballot(pos));
    c[1] = __popcll(__ballot(nm));
    c[2] = __popcll(__ballot(np));
    #pragma unroll
    for (int k = 0; k < NLAD; ++k){
      float L = LADV[k];
      c[3 + k]  = __popcll(__ballot(pos && sp > L));
      c[10 + k] = __popcll(__ballot(nm  && sn > L));
      c[17 + k] = __popcll(__ballot(np  && sn > L));
    }
    if (t == 0){
      #pragma unroll
      for (int k = 0; k < 24; ++k) cnts_part[b * 24 + k] = c[k];
    }
  }
}

// ---- K2: blocks [0,n2): per-GT reduce + forced scatter + exact corrections;
//          blocks [n2, n2+24): sum provisional counter columns into cnts ----
__global__ __launch_bounds__(TPB)
void colfix_kernel(const ull* __restrict__ colpart, int n1, int n2, int nblk,
                   const float* __restrict__ max_iou,
                   const float* __restrict__ pn, const float* __restrict__ nn,
                   int* __restrict__ forced, const int* __restrict__ cnts_part,
                   int* __restrict__ cnts)
{
  const int t = threadIdx.x;
  __shared__ ull red[TPB];
  __shared__ int ired[TPB];

  if (blockIdx.x < (unsigned)n2){
    const int jj = blockIdx.x;
    ull m = 0;
    for (int x = t; x < nblk; x += TPB){
      ull v = colpart[(size_t)x * n2 + jj];
      if (v > m) m = v;
    }
    red[t] = m;
    __syncthreads();
    for (int s = TPB >> 1; s > 0; s >>= 1){
      if (t < s && red[t + s] > red[t]) red[t] = red[t + s];
      __syncthreads();
    }
    if (t == 0){
      unsigned idx = ~(unsigned)(red[0] & 0xFFFFFFFFull);
      if (idx < (unsigned)n1){
        int old = atomicExch(&forced[idx], 1);    // dedupe: first claimer corrects
        if (old == 0){
          float m2 = max_iou[idx];
          if (!(m2 > HIGHT)){                     // forcing flips this row to pos
            float sp = pn[idx];
            float sn = nn[idx];
            atomicAdd(&cnts[0], 1);
            atomicAdd(&cnts[2], -1);
            #pragma unroll
            for (int k = 0; k < NLAD; ++k){
              float L = LADV[k];
              if (sp > L) atomicAdd(&cnts[3 + k], 1);
              if (sn > L) atomicAdd(&cnts[17 + k], -1);
            }
            if (m2 < LOWT){
              atomicAdd(&cnts[1], -1);
              #pragma unroll
              for (int k = 0; k < NLAD; ++k)
                if (sn > LADV[k]) atomicAdd(&cnts[10 + k], -1);
            }
          }
        }
      }
    }
  } else {
    const int k = blockIdx.x - n2;                // counter column 0..23
    int s = 0;
    for (int x = t; x < nblk; x += TPB) s += cnts_part[x * 24 + k];
    ired[t] = s;
    __syncthreads();
    for (int st = TPB >> 1; st > 0; st >>= 1){
      if (t < st) ired[t] += ired[t + st];
      __syncthreads();
    }
    if (t == 0 && ired[0]) atomicAdd(&cnts[k], ired[0]);
  }
}

// ---- tau: largest ladder level with >= KSEL survivors (exact superset) ----
__device__ __forceinline__ float pick_tau(const int* lad, int tot){
  if (tot <= CAP) return -1.0f;       // collect all masked (exact, covers fill)
  for (int k = 0; k < NLAD; ++k)
    if (lad[k] >= KSEL) return LADV[k];
  return -1.0f;
}

// ---- K3: grid-wide collect into global cand buffers ----
__global__ __launch_bounds__(TPB)
void collect_kernel(const float* __restrict__ max_iou, const int* __restrict__ forced,
                    const float* __restrict__ pn, const float* __restrict__ nn,
                    int n1, int* __restrict__ cnts, ull* __restrict__ cand)
{
  __shared__ int s_c[24];
  const int t = threadIdx.x;
  if (t < 24) s_c[t] = cnts[t];
  __syncthreads();
  const bool fb = (s_c[1] == 0);                 // no negatives -> complement of pos
  const int totP = s_c[0];
  const int totN = fb ? s_c[2] : s_c[1];
  const float tauP = pick_tau(&s_c[3], totP);
  const float tauN = pick_tau(fb ? &s_c[17] : &s_c[10], totN);

  const int i = blockIdx.x * TPB + t;
  if (i >= n1) return;
  float m = max_iou[i];
  bool f = forced[i] != 0;
  bool pos = (m > HIGHT) || f;
  // Key: (bits(score)+1)<<32 | ~i (score in [0,1) -> bits monotone; +1 so the
  // fill key (k32=0) loses to a real 0.0 score).
  if (pos){
    float sc = pn[i];
    if (sc > tauP){
      int p = atomicAdd(&cnts[24], 1);
      if (p < CAP) cand[p] = ((ull)(__float_as_uint(sc) + 1u) << 32) | (ull)(unsigned)~(unsigned)i;
    }
  } else if (totP < KSEL && i < 2 * KSEL){
    // ref top_k fills with -1-scored entries in ascending index; all needed
    // fills have index < 2*KSEL
    int p = atomicAdd(&cnts[24], 1);
    if (p < CAP) cand[p] = (ull)(unsigned)~(unsigned)i;
  }
  bool seln = fb ? (!pos) : ((m < LOWT) && !f);
  if (seln){
    float sc = nn[i];
    if (sc > tauN){
      int p = atomicAdd(&cnts[25], 1);
      if (p < CAP) cand[CAP + p] = ((ull)(__float_as_uint(sc) + 1u) << 32) | (ull)(unsigned)~(unsigned)i;
    }
  } else if (totN < KSEL && i < 2 * KSEL){
    int p = atomicAdd(&cnts[25], 1);
    if (p < CAP) cand[CAP + p] = (ull)(unsigned)~(unsigned)i;
  }
}

// ---- K4: exact rank-select of top-128 per mode (keys totally ordered, unique) ----
__global__ __launch_bounds__(1024)
void select_kernel(const ull* __restrict__ cand, const int* __restrict__ cnts,
                   const int* __restrict__ input_idx, int* __restrict__ out)
{
  const int t = threadIdx.x;
  const bool isPos = (blockIdx.x == 0);
  __shared__ ull keys[CAP];
  int n = cnts[isPos ? 24 : 25]; if (n > CAP) n = CAP;
  for (int x = t; x < n; x += 1024)
    keys[x] = cand[(isPos ? 0 : CAP) + x];
  __syncthreads();
  ull mk[2]; int mr[2]; int ne = 0;
  for (int x = t; x < n; x += 1024){ mk[ne] = keys[x]; mr[ne] = 0; ++ne; }
  for (int o = 0; o < n; ++o){
    ull ko = keys[o];                             // uniform addr -> LDS broadcast
    if (ne > 0) mr[0] += (ko > mk[0]);
    if (ne > 1) mr[1] += (ko > mk[1]);
  }
  for (int e = 0; e < ne; ++e){
    int r = mr[e];
    if (r < KSEL){
      unsigned idx = ~(unsigned)(mk[e] & 0xFFFFFFFFull);
      if (isPos){ out[r] = (int)idx; out[KSEL + r] = input_idx[idx]; }
      else        out[2 * KSEL + r] = (int)idx;
    }
  }
}

extern "C" void kernel_launch(void* const* d_in, const int* in_sizes, int n_in,
                              void* d_out, int out_size, void* d_ws, size_t ws_size,
                              hipStream_t stream){
  const float4* boxes = (const float4*)d_in[0];
  const float4* gts   = (const float4*)d_in[1];
  const float* pos_noise = (const float*)d_in[2];
  const float* neg_noise = (const float*)d_in[3];
  const int n1 = in_sizes[0] / 4;
  const int n2 = in_sizes[1] / 4;
  int* out = (int*)d_out;

  char* ws = (char*)d_ws;
  size_t off = 0;
  auto carve = [&](size_t bytes) -> char* {
    char* p = ws + off;
    off = (off + bytes + 255) & ~(size_t)255;
    return p;
  };
  const int nblk = (n1 + CHUNK - 1) / CHUNK;       // 1563
  float* max_iou   = (float*)carve((size_t)n1 * 4);
  int*   input_idx = (int*)  carve((size_t)n1 * 4);
  ull*   colpart   = (ull*)  carve((size_t)nblk * n2 * 8);
  int*   forced    = (int*)  carve((size_t)n1 * 4);
  int*   cnts_part = (int*)  carve((size_t)nblk * 24 * 4);
  int*   cnts      = (int*)  carve(32 * 4);
  ull*   cand      = (ull*)  carve((size_t)2 * CAP * 8);

  const int gb = (n1 + TPB - 1) / TPB;             // 196
  fused_iou<<<nblk, TPB, 0, stream>>>(boxes, gts, n1, n2, nblk,
                                      max_iou, input_idx, colpart, forced,
                                      cnts_part, cnts, pos_noise, neg_noise);
  colfix_kernel<<<n2 + 24, TPB, 0, stream>>>(colpart, n1, n2, nblk, max_iou,
                                             pos_noise, neg_noise, forced, cnts_part, cnts);
  collect_kernel<<<gb, TPB, 0, stream>>>(max_iou, forced, pos_noise, neg_noise,
                                         n1, cnts, cand);
  select_kernel<<<2, 1024, 0, stream>>>(cand, cnts, input_idx, out);
}